// Round 6
// baseline (90.114 us; speedup 1.0000x reference)
//
#include <hip/hip_runtime.h>

typedef unsigned short u16;
typedef __attribute__((ext_vector_type(4))) unsigned short u16x4;
typedef __attribute__((ext_vector_type(8))) unsigned short u16x8;
typedef __attribute__((ext_vector_type(8))) short bf16x8;
typedef __attribute__((ext_vector_type(4))) float f32x4;

#define QN 512
#define SN 128
#define DN 512
#define QT 8192   /* query frames */
#define STF 2048  /* support frames */

#if __has_builtin(__builtin_amdgcn_exp2f)
#define EXP2F __builtin_amdgcn_exp2f
#else
#define EXP2F exp2f
#endif
#if __has_builtin(__builtin_amdgcn_logf)
#define LOG2F __builtin_amdgcn_logf
#else
#define LOG2F log2f
#endif

#define KEXP 2.8853900817779268f   /* 1/(lbda*ln2), lbda=0.5 */
#define CLOG 0.34657359027997264f  /* lbda*ln2 */
#define K2   7.38905609893065f     /* exp(1/lbda) = e^2 */

__device__ __forceinline__ u16 f2bf(float f){
  union { float f; unsigned int u; } v; v.f = f;
  unsigned int u = v.u;
  unsigned int r = (u + 0x7fffu + ((u >> 16) & 1u)) >> 16;
  return (u16)r;
}
__device__ __forceinline__ float bf2f(u16 v){
  union { unsigned int u; float f; } x; x.u = ((unsigned int)v) << 16; return x.f;
}

__device__ __forceinline__ void gld16(const void* g, unsigned lds_addr){
  __builtin_amdgcn_global_load_lds(
      (const __attribute__((address_space(1))) unsigned int*)(unsigned long long)g,
      (__attribute__((address_space(3))) unsigned int*)lds_addr,
      16, 0, 0);
}

// ---------------- prep: f32 -> NORMALIZED bf16 (row/||row||) ----------------
__global__ __launch_bounds__(256) void prep_kernel(
    const float* __restrict__ sup, const float* __restrict__ tgt,
    u16* __restrict__ Abf, u16* __restrict__ Bbf)
{
  int w = (int)((blockIdx.x * blockDim.x + threadIdx.x) >> 6);
  int lane = threadIdx.x & 63;
  if (w >= QT + STF) return;
  bool isQ = (w < QT);
  int row = isQ ? w : (w - QT);
  const float* src = (isQ ? tgt : sup) + (size_t)row * DN + lane * 8;
  f32x4 x0 = *(const f32x4*)src;
  f32x4 x1 = *(const f32x4*)(src + 4);
  float ss = 0.f;
  #pragma unroll
  for (int i = 0; i < 4; ++i) { ss += x0[i]*x0[i]; ss += x1[i]*x1[i]; }
  #pragma unroll
  for (int off = 32; off; off >>= 1) ss += __shfl_xor(ss, off);
  float inv = __builtin_amdgcn_rsqf(ss);   // 1/||row||; ||row|| ~ 22.6, no degenerate rows
  u16x8 o;
  #pragma unroll
  for (int i = 0; i < 4; ++i) { o[i] = f2bf(x0[i]*inv); o[i+4] = f2bf(x1[i]*inv); }
  u16* dst = (isQ ? Abf : Bbf) + (size_t)row * DN + lane * 8;
  *(u16x8*)dst = o;
}

// ---------------- fused: 256x128 MFMA GEMM (8 waves) -> 2x (LDS ed-tiles + DP) ----------
// 16 queries x 8 supports per block = 128 pairs; two epilogue+DP passes of 64 pairs
// (128 tasks x 512B = 64KB dt). GEMM: BK=32 double-buffer 2x24KB (union w/ dt),
// global_load_lds w16 linear dest + pre-swizzled source (granule ^ (row>>1)&3),
// R4-proven 2-barrier/iter discipline (per-wave vmcnt BEFORE barrier).
__global__ __launch_bounds__(512, 4) void fused_kernel(
    const u16* __restrict__ Abf, const u16* __restrict__ Bbf,
    float* __restrict__ out)
{
  __shared__ __align__(128) char smem[65536];
  const int t = threadIdx.x;
  // XCD swizzle: 512 blocks, 64 consecutive work-ids per XCD
  const int bid = blockIdx.x;
  const int wsw = (bid & 7) * 64 + (bid >> 3);
  const int bx = wsw & 15, by = wsw >> 4;
  const int m0 = by * 256;   // query-frame base
  const int n0 = bx * 128;   // support-frame base
  const int wave = t >> 6, lane = t & 63;
  const int wr = wave >> 1, wc = wave & 1;
  const int lhi = lane >> 4, llo = lane & 15;
  const int xg = (llo >> 1) & 3;

  const unsigned sbase = (unsigned)(unsigned long long)(void*)smem;

  // staging (per wave, 3 gld16/tile): A rows wave*32..+32 (2 instr), B rows wave*16..+16.
  // lane -> row lane>>2, phys granule lane&3 holds logical (lane&3)^((lane>>3)&3).
  const int rsub = lane >> 2;
  const int lg = (lane & 3) ^ ((lane >> 3) & 3);
  const u16* pA0 = Abf + (size_t)(m0 + wave*32 +  0 + rsub) * DN + lg*8;
  const u16* pA1 = Abf + (size_t)(m0 + wave*32 + 16 + rsub) * DN + lg*8;
  const u16* pB0 = Bbf + (size_t)(n0 + wave*16 + rsub) * DN + lg*8;
  const unsigned ldsA0 = __builtin_amdgcn_readfirstlane(sbase + (unsigned)(wave*2048));
  const unsigned ldsA1 = __builtin_amdgcn_readfirstlane(sbase + (unsigned)(wave*2048 + 1024));
  const unsigned ldsB0 = __builtin_amdgcn_readfirstlane(sbase + 16384u + (unsigned)(wave*1024));

  f32x4 acc[4][4] = {};

  auto STAGE = [&](int sel, int koff) {
    unsigned bo = (unsigned)sel * 24576u;
    gld16(pA0 + koff, ldsA0 + bo);
    gld16(pA1 + koff, ldsA1 + bo);
    gld16(pB0 + koff, ldsB0 + bo);
  };
  auto COMPUTE = [&](int sel) {
    const char* ba = smem + sel * 24576;
    const char* bb = ba + 16384;
    bf16x8 af[4], bfr[4];
    #pragma unroll
    for (int mi = 0; mi < 4; ++mi)
      af[mi] = *(const bf16x8*)(ba + (wr*64 + mi*16 + llo)*64 + ((lhi ^ xg) << 4));
    #pragma unroll
    for (int ni = 0; ni < 4; ++ni)
      bfr[ni] = *(const bf16x8*)(bb + (wc*64 + ni*16 + llo)*64 + ((lhi ^ xg) << 4));
    #pragma unroll
    for (int mi = 0; mi < 4; ++mi)
      #pragma unroll
      for (int ni = 0; ni < 4; ++ni)
        acc[mi][ni] = __builtin_amdgcn_mfma_f32_16x16x32_bf16(af[mi], bfr[ni], acc[mi][ni], 0, 0, 0);
  };

  STAGE(0, 0);
  #pragma unroll 1
  for (int it = 0; it < 16; ++it) {
    if (it < 15) {
      STAGE((it + 1) & 1, (it + 1) * 32);
      asm volatile("s_waitcnt vmcnt(3)" ::: "memory");  // own tile-it loads done
    } else {
      asm volatile("s_waitcnt vmcnt(0)" ::: "memory");
    }
    __builtin_amdgcn_s_barrier();                        // all waves' tile-it loads done
    asm volatile("" ::: "memory");
    COMPUTE(it & 1);
    asm volatile("" ::: "memory");
    __builtin_amdgcn_s_barrier();                        // readers done before overwrite
  }
  __syncthreads();  // smem about to be reused as dt

  // ---- two passes: epilogue (64 pairs -> 64KB dt) + DP ----
  // dt element (l,m) of task T at byte: T*512 + ((l*32+m*2) ^ ((l&12)<<3) ^ ((T&31)<<4))
  #pragma unroll 1
  for (int pass = 0; pass < 2; ++pass) {
    if ((wave >> 2) == pass) {   // waves 0-3 own q-half 0; waves 4-7 own q-half 1
      #pragma unroll
      for (int ni = 0; ni < 4; ++ni) {
        int sloc = wc*4 + ni;
        int ts = llo;
        #pragma unroll
        for (int mi = 0; mi < 4; ++mi) {
          int qq = (wr & 1)*4 + mi;       // q within this pass (0..7)
          int T0 = (qq*8 + sloc) * 2;
          int T1 = T0 + 1;
          int swz0 = (T0 & 31) << 4, swz1 = (T1 & 31) << 4;
          u16x4 pk;
          #pragma unroll
          for (int j = 0; j < 4; ++j) {
            int tq = lhi*4 + j;
            // inputs pre-normalized: cos = acc; ed = exp2((cos-1)*KEXP)
            float ed = EXP2F(fmaf(acc[mi][ni][j], KEXP, -KEXP));
            u16 e16 = f2bf(ed);
            pk[j] = e16;
            *(u16*)(smem + T0*512 + ((tq*32 + ts*2) ^ ((tq&12)<<3) ^ swz0)) = e16;
          }
          *(u16x4*)(smem + T1*512 + ((ts*32 + lhi*8) ^ ((ts&12)<<3) ^ swz1)) = pk;
        }
      }
    }
    __syncthreads();

    if (t < 128) {
      const char* tb = smem + t * 512;
      const int swz = (t & 31) << 4;
      float F[18];
      {
        u16x8 g0 = *(const u16x8*)(tb + (0 ^ swz));
        u16x8 g1 = *(const u16x8*)(tb + (16 ^ swz));
        float c = 1.0f;
        F[0] = 1.0f;
        #pragma unroll
        for (int m = 1; m <= 8; ++m)  { c *= bf2f(g0[m-1]); F[m] = c; }
        #pragma unroll
        for (int m = 9; m <= 16; ++m) { c *= bf2f(g1[m-9]); F[m] = c; }
        F[17] = c;
      }
      u16x8 h0 = *(const u16x8*)(tb + ((32 ^ ((1&12)<<3)) ^ swz));
      u16x8 h1 = *(const u16x8*)(tb + (((32+16) ^ ((1&12)<<3)) ^ swz));
      float rowc = 1.0f;
      #pragma unroll 1
      for (int l = 1; l < 16; ++l) {
        u16x8 n0v, n1v;
        if (l < 15) {
          int lb = (l+1)*32, lx = ((l+1)&12)<<3;
          n0v = *(const u16x8*)(tb + ((lb ^ lx) ^ swz));
          n1v = *(const u16x8*)(tb + (((lb+16) ^ lx) ^ swz));
        }
        rowc *= K2;
        float e[16];
        #pragma unroll
        for (int m = 0; m < 8; ++m)  e[m]   = bf2f(h0[m]);
        #pragma unroll
        for (int m = 0; m < 8; ++m)  e[m+8] = bf2f(h1[m]);
        float c[18];
        c[1] = e[0]*K2*(F[0] + F[1]);            // edge m=1: 3 preds
        #pragma unroll
        for (int m = 2; m <= 16; ++m) c[m] = e[m-1]*K2*F[m-1];
        c[17] = K2*(F[16] + F[17]);              // edge m=17: 3 preds, ed=1
        F[0] = rowc;
        #pragma unroll
        for (int m = 1; m <= 16; ++m) F[m] = fmaf(e[m-1], F[m-1], c[m]);
        F[17] = F[16] + c[17];
        h0 = n0v; h1 = n1v;
      }
      float res = 15.0f - CLOG * LOG2F(F[17]);
      float other = __shfl_xor(res, 1);
      if (!(t & 1)) {
        int pair = t >> 1;
        int ql = (pair >> 3) + pass*8, sl = pair & 7;
        out[(size_t)(by*16 + ql) * SN + bx*8 + sl] = res + other;
      }
    }
    __syncthreads();  // dt consumed before pass-1 epilogue overwrites
  }
}

// ---------------- launch ----------------
extern "C" void kernel_launch(void* const* d_in, const int* in_sizes, int n_in,
                              void* d_out, int out_size, void* d_ws, size_t ws_size,
                              hipStream_t stream)
{
  const float* sup = (const float*)d_in[0];  // [128,16,512]
  const float* tgt = (const float*)d_in[1];  // [512,16,512]
  float* out = (float*)d_out;                // [512,128]
  char* ws = (char*)d_ws;

  u16* Abf = (u16*)(ws);                     // 8192*512*2 = 8,388,608
  u16* Bbf = (u16*)(ws + 8388608);           // 2048*512*2 = 2,097,152

  prep_kernel<<<dim3((QT + STF) / 4), dim3(256), 0, stream>>>(sup, tgt, Abf, Bbf);
  fused_kernel<<<dim3(512), dim3(512), 0, stream>>>(Abf, Bbf, out);
}

// Round 7
// 53.564 us; speedup vs baseline: 1.6824x; 1.6824x over previous
//
#include <hip/hip_runtime.h>

typedef unsigned short u16;
typedef __attribute__((ext_vector_type(4))) unsigned short u16x4;
typedef __attribute__((ext_vector_type(8))) unsigned short u16x8;
typedef __attribute__((ext_vector_type(8))) short bf16x8;
typedef __attribute__((ext_vector_type(4))) float f32x4;

#define QN 512
#define SN 128
#define DN 512
#define QT 8192   /* query frames */
#define STF 2048  /* support frames */

#if __has_builtin(__builtin_amdgcn_exp2f)
#define EXP2F __builtin_amdgcn_exp2f
#else
#define EXP2F exp2f
#endif
#if __has_builtin(__builtin_amdgcn_logf)
#define LOG2F __builtin_amdgcn_logf
#else
#define LOG2F log2f
#endif

#define KEXP 2.8853900817779268f   /* 1/(lbda*ln2), lbda=0.5 */
#define CLOG 0.34657359027997264f  /* lbda*ln2 */
#define K2   7.38905609893065f     /* exp(1/lbda) = e^2 */

__device__ __forceinline__ u16 f2bf(float f){
  union { float f; unsigned int u; } v; v.f = f;
  unsigned int u = v.u;
  unsigned int r = (u + 0x7fffu + ((u >> 16) & 1u)) >> 16;
  return (u16)r;
}
__device__ __forceinline__ float bf2f(u16 v){
  union { unsigned int u; float f; } x; x.u = ((unsigned int)v) << 16; return x.f;
}

__device__ __forceinline__ void gld16(const void* g, unsigned lds_addr){
  __builtin_amdgcn_global_load_lds(
      (const __attribute__((address_space(1))) unsigned int*)(unsigned long long)g,
      (__attribute__((address_space(3))) unsigned int*)lds_addr,
      16, 0, 0);
}

// ---------------- prep: f32 -> NORMALIZED bf16 (row/||row||) ----------------
__global__ __launch_bounds__(256) void prep_kernel(
    const float* __restrict__ sup, const float* __restrict__ tgt,
    u16* __restrict__ Abf, u16* __restrict__ Bbf)
{
  int w = (int)((blockIdx.x * blockDim.x + threadIdx.x) >> 6);
  int lane = threadIdx.x & 63;
  if (w >= QT + STF) return;
  bool isQ = (w < QT);
  int row = isQ ? w : (w - QT);
  const float* src = (isQ ? tgt : sup) + (size_t)row * DN + lane * 8;
  f32x4 x0 = *(const f32x4*)src;
  f32x4 x1 = *(const f32x4*)(src + 4);
  float ss = 0.f;
  #pragma unroll
  for (int i = 0; i < 4; ++i) { ss += x0[i]*x0[i]; ss += x1[i]*x1[i]; }
  #pragma unroll
  for (int off = 32; off; off >>= 1) ss += __shfl_xor(ss, off);
  float inv = __builtin_amdgcn_rsqf(ss);   // 1/||row||; ||row|| ~ 22.6, no degenerate rows
  u16x8 o;
  #pragma unroll
  for (int i = 0; i < 4; ++i) { o[i] = f2bf(x0[i]*inv); o[i+4] = f2bf(x1[i]*inv); }
  u16* dst = (isQ ? Abf : Bbf) + (size_t)row * DN + lane * 8;
  *(u16x8*)dst = o;
}

// ---------------- fused: 256x128 MFMA GEMM (8 waves) -> 2x (LDS ed-tiles + DP) ----------
// 16 queries x 8 supports per block = 128 pairs; two epilogue+DP passes of 64 pairs
// (128 tasks x 512B = 64KB dt). GEMM: BK=32 double-buffer 2x24KB (union w/ dt),
// global_load_lds w16 linear dest + pre-swizzled source (granule ^ (row>>1)&3),
// 2-barrier/iter discipline (per-wave vmcnt BEFORE barrier).
// NOTE: min-waves arg must stay ≥ VGPR need — (512,4) forced VGPR=64 and spilled (R6).
__global__ __launch_bounds__(512, 2) void fused_kernel(
    const u16* __restrict__ Abf, const u16* __restrict__ Bbf,
    float* __restrict__ out)
{
  __shared__ __align__(128) char smem[65536];
  const int t = threadIdx.x;
  // XCD swizzle: 512 blocks, 64 consecutive work-ids per XCD
  const int bid = blockIdx.x;
  const int wsw = (bid & 7) * 64 + (bid >> 3);
  const int bx = wsw & 15, by = wsw >> 4;
  const int m0 = by * 256;   // query-frame base
  const int n0 = bx * 128;   // support-frame base
  const int wave = t >> 6, lane = t & 63;
  const int wr = wave >> 1, wc = wave & 1;
  const int lhi = lane >> 4, llo = lane & 15;
  const int xg = (llo >> 1) & 3;

  const unsigned sbase = (unsigned)(unsigned long long)(void*)smem;

  // staging (per wave, 3 gld16/tile): A rows wave*32..+32 (2 instr), B rows wave*16..+16.
  // lane -> row lane>>2, phys granule lane&3 holds logical (lane&3)^((lane>>3)&3).
  const int rsub = lane >> 2;
  const int lg = (lane & 3) ^ ((lane >> 3) & 3);
  const u16* pA0 = Abf + (size_t)(m0 + wave*32 +  0 + rsub) * DN + lg*8;
  const u16* pA1 = Abf + (size_t)(m0 + wave*32 + 16 + rsub) * DN + lg*8;
  const u16* pB0 = Bbf + (size_t)(n0 + wave*16 + rsub) * DN + lg*8;
  const unsigned ldsA0 = __builtin_amdgcn_readfirstlane(sbase + (unsigned)(wave*2048));
  const unsigned ldsA1 = __builtin_amdgcn_readfirstlane(sbase + (unsigned)(wave*2048 + 1024));
  const unsigned ldsB0 = __builtin_amdgcn_readfirstlane(sbase + 16384u + (unsigned)(wave*1024));

  f32x4 acc[4][4] = {};

  auto STAGE = [&](int sel, int koff) {
    unsigned bo = (unsigned)sel * 24576u;
    gld16(pA0 + koff, ldsA0 + bo);
    gld16(pA1 + koff, ldsA1 + bo);
    gld16(pB0 + koff, ldsB0 + bo);
  };
  auto COMPUTE = [&](int sel) {
    const char* ba = smem + sel * 24576;
    const char* bb = ba + 16384;
    bf16x8 af[4], bfr[4];
    #pragma unroll
    for (int mi = 0; mi < 4; ++mi)
      af[mi] = *(const bf16x8*)(ba + (wr*64 + mi*16 + llo)*64 + ((lhi ^ xg) << 4));
    #pragma unroll
    for (int ni = 0; ni < 4; ++ni)
      bfr[ni] = *(const bf16x8*)(bb + (wc*64 + ni*16 + llo)*64 + ((lhi ^ xg) << 4));
    #pragma unroll
    for (int mi = 0; mi < 4; ++mi)
      #pragma unroll
      for (int ni = 0; ni < 4; ++ni)
        acc[mi][ni] = __builtin_amdgcn_mfma_f32_16x16x32_bf16(af[mi], bfr[ni], acc[mi][ni], 0, 0, 0);
  };

  STAGE(0, 0);
  #pragma unroll 1
  for (int it = 0; it < 16; ++it) {
    if (it < 15) {
      STAGE((it + 1) & 1, (it + 1) * 32);
      asm volatile("s_waitcnt vmcnt(3)" ::: "memory");  // own tile-it loads done
    } else {
      asm volatile("s_waitcnt vmcnt(0)" ::: "memory");
    }
    __builtin_amdgcn_s_barrier();                        // all waves' tile-it loads done
    asm volatile("" ::: "memory");
    COMPUTE(it & 1);
    asm volatile("" ::: "memory");
    __builtin_amdgcn_s_barrier();                        // readers done before overwrite
  }
  __syncthreads();  // smem about to be reused as dt

  // ---- two passes: epilogue (64 pairs -> 64KB dt) + DP ----
  // dt element (l,m) of task T at byte: T*512 + ((l*32+m*2) ^ ((l&12)<<3) ^ ((T&31)<<4))
  #pragma unroll 1
  for (int pass = 0; pass < 2; ++pass) {
    if ((wave >> 2) == pass) {   // waves 0-3 own q-half 0; waves 4-7 own q-half 1
      #pragma unroll
      for (int ni = 0; ni < 4; ++ni) {
        int sloc = wc*4 + ni;
        int ts = llo;
        #pragma unroll
        for (int mi = 0; mi < 4; ++mi) {
          int qq = (wr & 1)*4 + mi;       // q within this pass (0..7)
          int T0 = (qq*8 + sloc) * 2;
          int T1 = T0 + 1;
          int swz0 = (T0 & 31) << 4, swz1 = (T1 & 31) << 4;
          u16x4 pk;
          #pragma unroll
          for (int j = 0; j < 4; ++j) {
            int tq = lhi*4 + j;
            // inputs pre-normalized: cos = acc; ed = exp2((cos-1)*KEXP)
            float ed = EXP2F(fmaf(acc[mi][ni][j], KEXP, -KEXP));
            u16 e16 = f2bf(ed);
            pk[j] = e16;
            *(u16*)(smem + T0*512 + ((tq*32 + ts*2) ^ ((tq&12)<<3) ^ swz0)) = e16;
          }
          *(u16x4*)(smem + T1*512 + ((ts*32 + lhi*8) ^ ((ts&12)<<3) ^ swz1)) = pk;
        }
      }
    }
    __syncthreads();

    if (t < 128) {
      const char* tb = smem + t * 512;
      const int swz = (t & 31) << 4;
      float F[18];
      {
        u16x8 g0 = *(const u16x8*)(tb + (0 ^ swz));
        u16x8 g1 = *(const u16x8*)(tb + (16 ^ swz));
        float c = 1.0f;
        F[0] = 1.0f;
        #pragma unroll
        for (int m = 1; m <= 8; ++m)  { c *= bf2f(g0[m-1]); F[m] = c; }
        #pragma unroll
        for (int m = 9; m <= 16; ++m) { c *= bf2f(g1[m-9]); F[m] = c; }
        F[17] = c;
      }
      u16x8 h0 = *(const u16x8*)(tb + ((32 ^ ((1&12)<<3)) ^ swz));
      u16x8 h1 = *(const u16x8*)(tb + (((32+16) ^ ((1&12)<<3)) ^ swz));
      float rowc = 1.0f;
      #pragma unroll 1
      for (int l = 1; l < 16; ++l) {
        u16x8 n0v, n1v;
        if (l < 15) {
          int lb = (l+1)*32, lx = ((l+1)&12)<<3;
          n0v = *(const u16x8*)(tb + ((lb ^ lx) ^ swz));
          n1v = *(const u16x8*)(tb + (((lb+16) ^ lx) ^ swz));
        }
        rowc *= K2;
        float e[16];
        #pragma unroll
        for (int m = 0; m < 8; ++m)  e[m]   = bf2f(h0[m]);
        #pragma unroll
        for (int m = 0; m < 8; ++m)  e[m+8] = bf2f(h1[m]);
        float c[18];
        c[1] = e[0]*K2*(F[0] + F[1]);            // edge m=1: 3 preds
        #pragma unroll
        for (int m = 2; m <= 16; ++m) c[m] = e[m-1]*K2*F[m-1];
        c[17] = K2*(F[16] + F[17]);              // edge m=17: 3 preds, ed=1
        F[0] = rowc;
        #pragma unroll
        for (int m = 1; m <= 16; ++m) F[m] = fmaf(e[m-1], F[m-1], c[m]);
        F[17] = F[16] + c[17];
        h0 = n0v; h1 = n1v;
      }
      float res = 15.0f - CLOG * LOG2F(F[17]);
      float other = __shfl_xor(res, 1);
      if (!(t & 1)) {
        int pair = t >> 1;
        int ql = (pair >> 3) + pass*8, sl = pair & 7;
        out[(size_t)(by*16 + ql) * SN + bx*8 + sl] = res + other;
      }
    }
    __syncthreads();  // dt consumed before pass-1 epilogue overwrites
  }
}

// ---------------- launch ----------------
extern "C" void kernel_launch(void* const* d_in, const int* in_sizes, int n_in,
                              void* d_out, int out_size, void* d_ws, size_t ws_size,
                              hipStream_t stream)
{
  const float* sup = (const float*)d_in[0];  // [128,16,512]
  const float* tgt = (const float*)d_in[1];  // [512,16,512]
  float* out = (float*)d_out;                // [512,128]
  char* ws = (char*)d_ws;

  u16* Abf = (u16*)(ws);                     // 8192*512*2 = 8,388,608
  u16* Bbf = (u16*)(ws + 8388608);           // 2048*512*2 = 2,097,152

  prep_kernel<<<dim3((QT + STF) / 4), dim3(256), 0, stream>>>(sup, tgt, Abf, Bbf);
  fused_kernel<<<dim3(512), dim3(512), 0, stream>>>(Abf, Bbf, out);
}

// Round 8
// 41.880 us; speedup vs baseline: 2.1517x; 1.2790x over previous
//
#include <hip/hip_runtime.h>

typedef unsigned short u16;
typedef __attribute__((ext_vector_type(4))) unsigned short u16x4;
typedef __attribute__((ext_vector_type(8))) unsigned short u16x8;
typedef __attribute__((ext_vector_type(8))) short bf16x8;
typedef __attribute__((ext_vector_type(4))) float f32x4;

#define QN 512
#define SN 128
#define DN 512
#define QT 8192   /* query frames */
#define STF 2048  /* support frames */

#if __has_builtin(__builtin_amdgcn_exp2f)
#define EXP2F __builtin_amdgcn_exp2f
#else
#define EXP2F exp2f
#endif
#if __has_builtin(__builtin_amdgcn_logf)
#define LOG2F __builtin_amdgcn_logf
#else
#define LOG2F log2f
#endif

#define KEXP 2.8853900817779268f   /* 1/(lbda*ln2), lbda=0.5 */
#define CLOG 0.34657359027997264f  /* lbda*ln2 */
#define K2   7.38905609893065f     /* exp(1/lbda) = e^2 */

__device__ __forceinline__ u16 f2bf(float f){
  union { float f; unsigned int u; } v; v.f = f;
  unsigned int u = v.u;
  unsigned int r = (u + 0x7fffu + ((u >> 16) & 1u)) >> 16;
  return (u16)r;
}
__device__ __forceinline__ float bf2f(u16 v){
  union { unsigned int u; float f; } x; x.u = ((unsigned int)v) << 16; return x.f;
}

__device__ __forceinline__ void gld16(const void* g, unsigned lds_addr){
  __builtin_amdgcn_global_load_lds(
      (const __attribute__((address_space(1))) unsigned int*)(unsigned long long)g,
      (__attribute__((address_space(3))) unsigned int*)lds_addr,
      16, 0, 0);
}

// ---------------- prep: f32 -> NORMALIZED bf16 (row/||row||) ----------------
__global__ __launch_bounds__(256) void prep_kernel(
    const float* __restrict__ sup, const float* __restrict__ tgt,
    u16* __restrict__ Abf, u16* __restrict__ Bbf)
{
  int w = (int)((blockIdx.x * blockDim.x + threadIdx.x) >> 6);
  int lane = threadIdx.x & 63;
  if (w >= QT + STF) return;
  bool isQ = (w < QT);
  int row = isQ ? w : (w - QT);
  const float* src = (isQ ? tgt : sup) + (size_t)row * DN + lane * 8;
  f32x4 x0 = *(const f32x4*)src;
  f32x4 x1 = *(const f32x4*)(src + 4);
  float ss = 0.f;
  #pragma unroll
  for (int i = 0; i < 4; ++i) { ss += x0[i]*x0[i]; ss += x1[i]*x1[i]; }
  #pragma unroll
  for (int off = 32; off; off >>= 1) ss += __shfl_xor(ss, off);
  float inv = __builtin_amdgcn_rsqf(ss);
  u16x8 o;
  #pragma unroll
  for (int i = 0; i < 4; ++i) { o[i] = f2bf(x0[i]*inv); o[i+4] = f2bf(x1[i]*inv); }
  u16* dst = (isQ ? Abf : Bbf) + (size_t)row * DN + lane * 8;
  *(u16x8*)dst = o;
}

// ---------------- fused: 256x128 MFMA GEMM (8 waves) -> 2x (LDS ed-tiles + DP) ----------
// Register discipline (the R8 change): acc dies at the epilogue for ALL waves.
// Waves 0-3 write pass-0 dt from acc; waves 4-7 pack acc -> 32 u32 (ed bf16) and
// unpack to dt after DP pass 0. Peak live stays <= ~105 so (512,4) fits 128 unified
// regs (4 waves/SIMD -> 2 blocks/CU with 64KB LDS) without spilling.
__global__ __launch_bounds__(512, 4) void fused_kernel(
    const u16* __restrict__ Abf, const u16* __restrict__ Bbf,
    float* __restrict__ out)
{
  __shared__ __align__(128) char smem[65536];
  const int t = threadIdx.x;
  // XCD swizzle: 512 blocks, 64 consecutive work-ids per XCD
  const int bid = blockIdx.x;
  const int wsw = (bid & 7) * 64 + (bid >> 3);
  const int bx = wsw & 15, by = wsw >> 4;
  const int m0 = by * 256;   // query-frame base
  const int n0 = bx * 128;   // support-frame base
  const int wave = t >> 6, lane = t & 63;
  const int wr = wave >> 1, wc = wave & 1;
  const int lhi = lane >> 4, llo = lane & 15;
  const int xg = (llo >> 1) & 3;

  const unsigned sbase = (unsigned)(unsigned long long)(void*)smem;

  // staging (per wave, 3 gld16/tile): A rows wave*32..+32 (2 instr), B rows wave*16..+16.
  const int rsub = lane >> 2;
  const int lg = (lane & 3) ^ ((lane >> 3) & 3);
  const u16* pA0 = Abf + (size_t)(m0 + wave*32 +  0 + rsub) * DN + lg*8;
  const u16* pA1 = Abf + (size_t)(m0 + wave*32 + 16 + rsub) * DN + lg*8;
  const u16* pB0 = Bbf + (size_t)(n0 + wave*16 + rsub) * DN + lg*8;
  const unsigned ldsA0 = __builtin_amdgcn_readfirstlane(sbase + (unsigned)(wave*2048));
  const unsigned ldsA1 = __builtin_amdgcn_readfirstlane(sbase + (unsigned)(wave*2048 + 1024));
  const unsigned ldsB0 = __builtin_amdgcn_readfirstlane(sbase + 16384u + (unsigned)(wave*1024));

  f32x4 acc[4][4] = {};

  auto STAGE = [&](int sel, int koff) {
    unsigned bo = (unsigned)sel * 24576u;
    gld16(pA0 + koff, ldsA0 + bo);
    gld16(pA1 + koff, ldsA1 + bo);
    gld16(pB0 + koff, ldsB0 + bo);
  };
  auto COMPUTE = [&](int sel) {
    const char* ba = smem + sel * 24576;
    const char* bb = ba + 16384;
    bf16x8 af[4], bfr[4];
    #pragma unroll
    for (int mi = 0; mi < 4; ++mi)
      af[mi] = *(const bf16x8*)(ba + (wr*64 + mi*16 + llo)*64 + ((lhi ^ xg) << 4));
    #pragma unroll
    for (int ni = 0; ni < 4; ++ni)
      bfr[ni] = *(const bf16x8*)(bb + (wc*64 + ni*16 + llo)*64 + ((lhi ^ xg) << 4));
    #pragma unroll
    for (int mi = 0; mi < 4; ++mi)
      #pragma unroll
      for (int ni = 0; ni < 4; ++ni)
        acc[mi][ni] = __builtin_amdgcn_mfma_f32_16x16x32_bf16(af[mi], bfr[ni], acc[mi][ni], 0, 0, 0);
  };

  STAGE(0, 0);
  #pragma unroll 1
  for (int it = 0; it < 16; ++it) {
    if (it < 15) {
      STAGE((it + 1) & 1, (it + 1) * 32);
      asm volatile("s_waitcnt vmcnt(3)" ::: "memory");  // own tile-it loads done
    } else {
      asm volatile("s_waitcnt vmcnt(0)" ::: "memory");
    }
    __builtin_amdgcn_s_barrier();                        // all waves' tile-it loads done
    asm volatile("" ::: "memory");
    COMPUTE(it & 1);
    asm volatile("" ::: "memory");
    __builtin_amdgcn_s_barrier();                        // readers done before overwrite
  }
  __syncthreads();  // smem about to be reused as dt

  // ---- epilogue: acc -> ed (bf16). Waves 0-3: straight to dt. Waves 4-7: pack to regs.
  // dt element (l,m) of task T at byte: T*512 + ((l*32+m*2) ^ ((l&12)<<3) ^ ((T&31)<<4))
  unsigned pack[32];
  const int ts = llo;
  if (wave < 4) {
    #pragma unroll
    for (int ni = 0; ni < 4; ++ni) {
      int sloc = wc*4 + ni;
      #pragma unroll
      for (int mi = 0; mi < 4; ++mi) {
        int qq = (wr & 1)*4 + mi;       // q within pass 0 (0..7)
        int T0 = (qq*8 + sloc) * 2;
        int T1 = T0 + 1;
        int swz0 = (T0 & 31) << 4, swz1 = (T1 & 31) << 4;
        u16x4 pk;
        #pragma unroll
        for (int j = 0; j < 4; ++j) {
          int tq = lhi*4 + j;
          float ed = EXP2F(fmaf(acc[mi][ni][j], KEXP, -KEXP));
          u16 e16 = f2bf(ed);
          pk[j] = e16;
          *(u16*)(smem + T0*512 + ((tq*32 + ts*2) ^ ((tq&12)<<3) ^ swz0)) = e16;
        }
        *(u16x4*)(smem + T1*512 + ((ts*32 + lhi*8) ^ ((ts&12)<<3) ^ swz1)) = pk;
      }
    }
  } else {
    #pragma unroll
    for (int ni = 0; ni < 4; ++ni)
      #pragma unroll
      for (int mi = 0; mi < 4; ++mi)
        #pragma unroll
        for (int jj = 0; jj < 2; ++jj) {
          float e0 = EXP2F(fmaf(acc[mi][ni][jj*2+0], KEXP, -KEXP));
          float e1 = EXP2F(fmaf(acc[mi][ni][jj*2+1], KEXP, -KEXP));
          pack[(ni*4+mi)*2+jj] = (unsigned)f2bf(e0) | ((unsigned)f2bf(e1) << 16);
        }
  }
  __syncthreads();

  // ---- DP lambda: exp-domain OTAM, one task per calling lane ----
  auto DP = [&](int task, int pass) {
    const char* tb = smem + task * 512;
    const int swz = (task & 31) << 4;
    float F[18];
    {
      u16x8 g0 = *(const u16x8*)(tb + (0 ^ swz));
      u16x8 g1 = *(const u16x8*)(tb + (16 ^ swz));
      float c = 1.0f;
      F[0] = 1.0f;
      #pragma unroll
      for (int m = 1; m <= 8; ++m)  { c *= bf2f(g0[m-1]); F[m] = c; }
      #pragma unroll
      for (int m = 9; m <= 16; ++m) { c *= bf2f(g1[m-9]); F[m] = c; }
      F[17] = c;
    }
    u16x8 h0 = *(const u16x8*)(tb + ((32 ^ ((1&12)<<3)) ^ swz));
    u16x8 h1 = *(const u16x8*)(tb + (((32+16) ^ ((1&12)<<3)) ^ swz));
    float rowc = 1.0f;
    #pragma unroll 1
    for (int l = 1; l < 16; ++l) {
      u16x8 n0v, n1v;
      if (l < 15) {
        int lb = (l+1)*32, lx = ((l+1)&12)<<3;
        n0v = *(const u16x8*)(tb + ((lb ^ lx) ^ swz));
        n1v = *(const u16x8*)(tb + (((lb+16) ^ lx) ^ swz));
      }
      rowc *= K2;
      float e[16];
      #pragma unroll
      for (int m = 0; m < 8; ++m)  e[m]   = bf2f(h0[m]);
      #pragma unroll
      for (int m = 0; m < 8; ++m)  e[m+8] = bf2f(h1[m]);
      float c[18];
      c[1] = e[0]*K2*(F[0] + F[1]);            // edge m=1: 3 preds
      #pragma unroll
      for (int m = 2; m <= 16; ++m) c[m] = e[m-1]*K2*F[m-1];
      c[17] = K2*(F[16] + F[17]);              // edge m=17: 3 preds, ed=1
      F[0] = rowc;
      #pragma unroll
      for (int m = 1; m <= 16; ++m) F[m] = fmaf(e[m-1], F[m-1], c[m]);
      F[17] = F[16] + c[17];
      h0 = n0v; h1 = n1v;
    }
    float res = 15.0f - CLOG * LOG2F(F[17]);
    float other = __shfl_xor(res, 1);
    if (!(task & 1)) {
      int pair = task >> 1;
      int ql = (pair >> 3) + pass*8, sl = pair & 7;
      out[(size_t)(by*16 + ql) * SN + bx*8 + sl] = res + other;
    }
  };

  // ---- DP pass 0: waves 0-1 ----
  if (t < 128) DP(t, 0);
  __syncthreads();

  // ---- waves 4-7: unpack ed regs -> dt for pass 1 ----
  if (wave >= 4) {
    #pragma unroll
    for (int ni = 0; ni < 4; ++ni) {
      int sloc = wc*4 + ni;
      #pragma unroll
      for (int mi = 0; mi < 4; ++mi) {
        int qq = (wr & 1)*4 + mi;       // q within pass 1 (0..7)
        int T0 = (qq*8 + sloc) * 2;
        int T1 = T0 + 1;
        int swz0 = (T0 & 31) << 4, swz1 = (T1 & 31) << 4;
        u16x4 pk;
        #pragma unroll
        for (int jj = 0; jj < 2; ++jj) {
          unsigned pv = pack[(ni*4+mi)*2+jj];
          u16 ea = (u16)(pv & 0xffffu), eb = (u16)(pv >> 16);
          pk[jj*2]   = ea;
          pk[jj*2+1] = eb;
          int tqa = lhi*4 + jj*2, tqb = tqa + 1;
          *(u16*)(smem + T0*512 + ((tqa*32 + ts*2) ^ ((tqa&12)<<3) ^ swz0)) = ea;
          *(u16*)(smem + T0*512 + ((tqb*32 + ts*2) ^ ((tqb&12)<<3) ^ swz0)) = eb;
        }
        *(u16x4*)(smem + T1*512 + ((ts*32 + lhi*8) ^ ((ts&12)<<3) ^ swz1)) = pk;
      }
    }
  }
  __syncthreads();

  // ---- DP pass 1: waves 4-5 ----
  if (t >= 256 && t < 384) DP(t - 256, 1);
}

// ---------------- launch ----------------
extern "C" void kernel_launch(void* const* d_in, const int* in_sizes, int n_in,
                              void* d_out, int out_size, void* d_ws, size_t ws_size,
                              hipStream_t stream)
{
  const float* sup = (const float*)d_in[0];  // [128,16,512]
  const float* tgt = (const float*)d_in[1];  // [512,16,512]
  float* out = (float*)d_out;                // [512,128]
  char* ws = (char*)d_ws;

  u16* Abf = (u16*)(ws);                     // 8192*512*2 = 8,388,608
  u16* Bbf = (u16*)(ws + 8388608);           // 2048*512*2 = 2,097,152

  prep_kernel<<<dim3((QT + STF) / 4), dim3(256), 0, stream>>>(sup, tgt, Abf, Bbf);
  fused_kernel<<<dim3(512), dim3(512), 0, stream>>>(Abf, Bbf, out);
}